// Round 6
// baseline (3957.941 us; speedup 1.0000x reference)
//
#include <hip/hip_runtime.h>

typedef unsigned short ushort;
typedef unsigned long long ull;
typedef __attribute__((ext_vector_type(8))) short short8;
typedef __attribute__((ext_vector_type(4))) float f32x4;
typedef __attribute__((ext_vector_type(4))) unsigned short us4;

// Problem constants
#define BB 32
#define TT 512
#define DIN 512
#define HH 1024
#define CHUNK 128

__device__ __forceinline__ ushort f2b(float f) {
  unsigned u = __builtin_bit_cast(unsigned, f);
  unsigned r = (u + 0x7fffu + ((u >> 16) & 1u)) >> 16;
  return (ushort)r;
}

#define MFMA16(a, b, c) __builtin_amdgcn_mfma_f32_16x16x32_bf16(a, b, c, 0, 0, 0)
#define AL(p) __hip_atomic_load((p), __ATOMIC_RELAXED, __HIP_MEMORY_SCOPE_AGENT)

union U8 { unsigned u[4]; short8 s; };

// ---------------------------------------------------------------- init
// zero slot 0 of h1_tr / h2_tr (16384 u32 each) + flags (2 x 128 ints)
__global__ __launch_bounds__(256) void init_k(unsigned int* h1s, unsigned int* h2s,
                                              int* f0, int* f1) {
  int i = blockIdx.x * 256 + threadIdx.x;   // grid 128 -> 32768
  if (i < 16384) h1s[i] = 0u;
  else h2s[i - 16384] = 0u;
  if (i < 128) f0[i] = 0;
  else if (i < 256) f1[i - 128] = 0;
}

// ---------------------------------------------------------------- fp32 -> bf16 cast
__global__ __launch_bounds__(256) void cast_k(const float* __restrict__ in,
                                              ushort* __restrict__ out, int n4) {
  int i = blockIdx.x * 256 + threadIdx.x;
  if (i < n4) {
    float4 v = ((const float4*)in)[i];
    us4 o;
    o.x = f2b(v.x); o.y = f2b(v.y); o.z = f2b(v.z); o.w = f2b(v.w);
    ((us4*)out)[i] = o;
  }
}

// ---------------------------------------------------------------- bf16 GEMM  C = A @ B^T
// A = fp32 x [B,T,DIN] (cast on the fly), row m -> x[(m&31)*TT + tOff + (m>>5)].
__global__ __launch_bounds__(256) void gemm_bt(const float* __restrict__ A32,
                                               const ushort* __restrict__ B,
                                               float* __restrict__ C,
                                               int N, int K, int tOff) {
  __shared__ __align__(16) ushort As[128 * 72];
  __shared__ __align__(16) ushort Bs[128 * 72];
  const int tid = threadIdx.x;
  const int lane = tid & 63, wave = tid >> 6;
  const int wm = wave >> 1, wn = wave & 1;
  const int bm = blockIdx.y << 7, bn = blockIdx.x << 7;

  const int srow = tid >> 3;
  const int sdst = (tid & 7) << 3;
  size_t aoff[4], boff[4];
#pragma unroll
  for (int i = 0; i < 4; ++i) {
    int m = bm + srow + (i << 5);
    aoff[i] = ((size_t)(m & 31) * TT + tOff + (m >> 5)) * (size_t)K;
    boff[i] = (size_t)(bn + srow + (i << 5)) * K;
  }

  const int fr = lane & 15, fq = lane >> 4;
  int aofl[4], bofl[4];
#pragma unroll
  for (int m = 0; m < 4; ++m) {
    aofl[m] = ((wm << 6) + (m << 4) + fr) * 72 + (fq << 3);
    bofl[m] = ((wn << 6) + (m << 4) + fr) * 72 + (fq << 3);
  }

  f32x4 acc[4][4] = {};
  for (int k0 = 0; k0 < K; k0 += 64) {
#pragma unroll
    for (int i = 0; i < 4; ++i) {
      int row = srow + (i << 5);
      float4 v0 = *(const float4*)&A32[aoff[i] + k0 + sdst];
      float4 v1 = *(const float4*)&A32[aoff[i] + k0 + sdst + 4];
      us4 lo, hi;
      lo.x = f2b(v0.x); lo.y = f2b(v0.y); lo.z = f2b(v0.z); lo.w = f2b(v0.w);
      hi.x = f2b(v1.x); hi.y = f2b(v1.y); hi.z = f2b(v1.z); hi.w = f2b(v1.w);
      *(us4*)&As[row * 72 + sdst] = lo;
      *(us4*)&As[row * 72 + sdst + 4] = hi;
      *(short8*)&Bs[row * 72 + sdst] = *(const short8*)&B[boff[i] + k0 + sdst];
    }
    __syncthreads();
#pragma unroll
    for (int kk = 0; kk < 2; ++kk) {
      short8 af[4], bf[4];
#pragma unroll
      for (int m = 0; m < 4; ++m) af[m] = *(const short8*)&As[aofl[m] + kk * 32];
#pragma unroll
      for (int n = 0; n < 4; ++n) bf[n] = *(const short8*)&Bs[bofl[n] + kk * 32];
#pragma unroll
      for (int m = 0; m < 4; ++m)
#pragma unroll
        for (int n = 0; n < 4; ++n)
          acc[m][n] = MFMA16(af[m], bf[n], acc[m][n]);
    }
    __syncthreads();
  }
#pragma unroll
  for (int m = 0; m < 4; ++m) {
    int row0 = bm + (wm << 6) + (m << 4) + (fq << 2);
#pragma unroll
    for (int n = 0; n < 4; ++n) {
      int col = bn + (wn << 6) + (n << 4) + fr;
#pragma unroll
      for (int r = 0; r < 4; ++r)
        C[(size_t)(row0 + r) * N + col] = acc[m][n][r];
    }
  }
}

// ---------------------------------------------------------------- fused 2-layer GRU
// 128 WGs x 512 thr (8 waves). WGs 0..63 layer 0, 64..127 layer 1 (one step behind,
// computes Wih1@h1 on the fly). h exchange buffers are TRANSPOSED: h_tr[c][b]
// (32 b per row = 64B rows). Each WG publishes its 16 c-rows as one contiguous 1KB
// block via coalesced 8B agent-scope stores (full-line write-combining), then
// vmcnt(0) + per-wave flag. Consumers poll 128 flags (agent loads), then gather
// h with plain cached loads (write-once addresses; L2-shared within each XCD).
__global__ __launch_bounds__(512, 2) void gru_fused(
    const ushort* __restrict__ wh0, const ushort* __restrict__ wh1,
    const ushort* __restrict__ wi1,
    const float* __restrict__ bih0, const float* __restrict__ bhh0,
    const float* __restrict__ bih1, const float* __restrict__ bhh1,
    const float* __restrict__ xp,
    ushort* __restrict__ h1t, ushort* __restrict__ h2t,
    float* __restrict__ hs0, float* __restrict__ hs1,
    int* __restrict__ f0, int* __restrict__ f1,
    int t0, int nSteps) {
  __shared__ float P[8][24][64];   // 48 KB partials
  const int tid = threadIdx.x;
  const int wv = tid >> 6, lane = tid & 63;
  const int fr = lane & 15, fq = lane >> 4;
  const int layer = blockIdx.x >> 6;
  const int wg = blockIdx.x & 63;
  const int c0 = wg << 4;
  const int c = c0 + fr;

  if (layer == 0) {
    // ================= layer 0 =================
    const int K0 = wv << 7;   // 8 waves x 128 K
    short8 wf[3][4];
#pragma unroll
    for (int g = 0; g < 3; ++g)
#pragma unroll
      for (int j = 0; j < 4; ++j)
        wf[g][j] = *(const short8*)&wh0[(size_t)(g * HH + c) * HH + K0 + j * 32 + fq * 8];

    float bhr = 0, bhz = 0, bhn = 0, bir = 0, biz = 0, bin_ = 0;
    float hl[4] = {};
    if (wv < 2) {
      bhr = bhh0[c]; bhz = bhh0[HH + c]; bhn = bhh0[2 * HH + c];
      bir = bih0[c]; biz = bih0[HH + c]; bin_ = bih0[2 * HH + c];
      if (t0 > 0)
#pragma unroll
        for (int r = 0; r < 4; ++r) hl[r] = hs0[(wv * 16 + (fq << 2) + r) * HH + c];
    }

    for (int i = 0; i < nSteps; ++i) {
      const int t = t0 + i;
      float xr[4], xz[4], xn[4];
      if (wv < 2) {
        const float* xpt = xp + (size_t)i * (BB * 3 * HH);
#pragma unroll
        for (int r = 0; r < 4; ++r) {
          const float* p = xpt + (size_t)(wv * 16 + (fq << 2) + r) * (3 * HH) + c;
          xr[r] = p[0]; xz[r] = p[HH]; xn[r] = p[2 * HH];
        }
      }
      asm volatile("" ::: "memory");
      {  // wait for h1_tr[slot i] (flag value t)
        int v0, v1;
        do {
          v0 = AL(f0 + lane); v1 = AL(f0 + 64 + lane);
          if (v0 < t || v1 < t) __builtin_amdgcn_s_sleep(1);
        } while (__any(v0 < t || v1 < t));
      }
      asm volatile("" ::: "memory");

      // gather A-fragments from h_tr[c][b]: a0 b=fr, a1 b=fr+16 (plain cached loads)
      const ushort* sb = h1t + (size_t)i * 32768;
      short8 a0[4], a1[4];
#pragma unroll
      for (int j = 0; j < 4; ++j) {
        const ushort* p = sb + ((K0 + j * 32 + fq * 8) << 5) + fr;
        U8 x0, x1;
#pragma unroll
        for (int q = 0; q < 4; ++q) {
          x0.u[q] = (unsigned)p[(2 * q) * 32] | ((unsigned)p[(2 * q + 1) * 32] << 16);
          x1.u[q] = (unsigned)p[(2 * q) * 32 + 16] | ((unsigned)p[(2 * q + 1) * 32 + 16] << 16);
        }
        a0[j] = x0.s; a1[j] = x1.s;
      }
      f32x4 acc[2][3] = {};
#pragma unroll
      for (int j = 0; j < 4; ++j) {
        acc[0][0] = MFMA16(a0[j], wf[0][j], acc[0][0]);
        acc[0][1] = MFMA16(a0[j], wf[1][j], acc[0][1]);
        acc[0][2] = MFMA16(a0[j], wf[2][j], acc[0][2]);
        acc[1][0] = MFMA16(a1[j], wf[0][j], acc[1][0]);
        acc[1][1] = MFMA16(a1[j], wf[1][j], acc[1][1]);
        acc[1][2] = MFMA16(a1[j], wf[2][j], acc[1][2]);
      }
#pragma unroll
      for (int mt = 0; mt < 2; ++mt)
#pragma unroll
        for (int g = 0; g < 3; ++g)
#pragma unroll
          for (int r = 0; r < 4; ++r)
            P[wv][mt * 12 + g * 4 + r][lane] = acc[mt][g][r];
      __syncthreads();

      if (wv < 2) {
        float s[3][4];
#pragma unroll
        for (int g = 0; g < 3; ++g)
#pragma unroll
          for (int r = 0; r < 4; ++r) {
            int e = wv * 12 + g * 4 + r;
            float v = 0.f;
#pragma unroll
            for (int w = 0; w < 8; ++w) v += P[w][e][lane];
            s[g][r] = v;
          }
        float hv[4];
#pragma unroll
        for (int r = 0; r < 4; ++r) {
          float rv = 1.f / (1.f + __expf(-(xr[r] + bir + s[0][r] + bhr)));
          float zv = 1.f / (1.f + __expf(-(xz[r] + biz + s[1][r] + bhz)));
          float nv = tanhf(xn[r] + bin_ + rv * (s[2][r] + bhn));
          hv[r] = (1.f - zv) * nv + zv * hl[r];
          hl[r] = hv[r];
        }
        ull word = (ull)((unsigned)f2b(hv[0]) | ((unsigned)f2b(hv[1]) << 16)) |
                   ((ull)((unsigned)f2b(hv[2]) | ((unsigned)f2b(hv[3]) << 16)) << 32);
        const int toff = (c0 + fr) * 32 + wv * 16 + fq * 4;   // ushort index in h_tr
        __hip_atomic_store((ull*)(h1t + (size_t)(i + 1) * 32768 + toff), word,
                           __ATOMIC_RELAXED, __HIP_MEMORY_SCOPE_AGENT);
        if (i == nSteps - 1) {
          *(ull*)(h1t + toff) = word;   // slot 0 for next launch (boundary-flushed)
#pragma unroll
          for (int r = 0; r < 4; ++r)
            hs0[(wv * 16 + (fq << 2) + r) * HH + c] = hv[r];
        }
        asm volatile("s_waitcnt vmcnt(0)" ::: "memory");
        if (lane == 0)
          __hip_atomic_store(f0 + wv * 64 + wg, t + 1,
                             __ATOMIC_RELAXED, __HIP_MEMORY_SCOPE_AGENT);
      }
      __syncthreads();
    }
  } else {
    // ================= layer 1 =================
    const int K0 = (wv & 3) << 8;   // 4+4 waves x 256 K
    const ushort* Wm = (wv < 4) ? wh1 : wi1;
    short8 wf[3][8];
#pragma unroll
    for (int g = 0; g < 3; ++g)
#pragma unroll
      for (int j = 0; j < 8; ++j)
        wf[g][j] = *(const short8*)&Wm[(size_t)(g * HH + c) * HH + K0 + j * 32 + fq * 8];

    float bhr = 0, bhz = 0, bhn = 0, bir = 0, biz = 0, bin_ = 0;
    float hl[4] = {};
    if (wv < 2) {
      bhr = bhh1[c]; bhz = bhh1[HH + c]; bhn = bhh1[2 * HH + c];
      bir = bih1[c]; biz = bih1[HH + c]; bin_ = bih1[2 * HH + c];
      if (t0 > 0)
#pragma unroll
        for (int r = 0; r < 4; ++r) hl[r] = hs1[(wv * 16 + (fq << 2) + r) * HH + c];
    }

    for (int i = 0; i < nSteps; ++i) {
      const int t = t0 + i;
      {  // need h2_tr[slot i] (f1 >= t) AND h1_tr[slot i+1] (f0 >= t+1)
        int ok;
        do {
          int a = AL(f1 + lane), b = AL(f1 + 64 + lane);
          int d = AL(f0 + lane), e = AL(f0 + 64 + lane);
          ok = (a >= t) && (b >= t) && (d >= t + 1) && (e >= t + 1);
          if (!ok) __builtin_amdgcn_s_sleep(1);
        } while (__any(!ok));
      }
      asm volatile("" ::: "memory");

      const ushort* sb = (wv < 4) ? h2t + (size_t)i * 32768
                                  : h1t + (size_t)(i + 1) * 32768;
      f32x4 acc[2][3] = {};
      {
        short8 a0[8];
#pragma unroll
        for (int j = 0; j < 8; ++j) {
          const ushort* p = sb + ((K0 + j * 32 + fq * 8) << 5) + fr;
          U8 x0;
#pragma unroll
          for (int q = 0; q < 4; ++q)
            x0.u[q] = (unsigned)p[(2 * q) * 32] | ((unsigned)p[(2 * q + 1) * 32] << 16);
          a0[j] = x0.s;
        }
#pragma unroll
        for (int j = 0; j < 8; ++j) {
          acc[0][0] = MFMA16(a0[j], wf[0][j], acc[0][0]);
          acc[0][1] = MFMA16(a0[j], wf[1][j], acc[0][1]);
          acc[0][2] = MFMA16(a0[j], wf[2][j], acc[0][2]);
        }
      }
      {
        short8 a1[8];
#pragma unroll
        for (int j = 0; j < 8; ++j) {
          const ushort* p = sb + ((K0 + j * 32 + fq * 8) << 5) + fr + 16;
          U8 x1;
#pragma unroll
          for (int q = 0; q < 4; ++q)
            x1.u[q] = (unsigned)p[(2 * q) * 32] | ((unsigned)p[(2 * q + 1) * 32] << 16);
          a1[j] = x1.s;
        }
#pragma unroll
        for (int j = 0; j < 8; ++j) {
          acc[1][0] = MFMA16(a1[j], wf[0][j], acc[1][0]);
          acc[1][1] = MFMA16(a1[j], wf[1][j], acc[1][1]);
          acc[1][2] = MFMA16(a1[j], wf[2][j], acc[1][2]);
        }
      }
#pragma unroll
      for (int mt = 0; mt < 2; ++mt)
#pragma unroll
        for (int g = 0; g < 3; ++g)
#pragma unroll
          for (int r = 0; r < 4; ++r)
            P[wv][mt * 12 + g * 4 + r][lane] = acc[mt][g][r];
      __syncthreads();

      if (wv < 2) {
        float sh[3][4], sx[3][4];
#pragma unroll
        for (int g = 0; g < 3; ++g)
#pragma unroll
          for (int r = 0; r < 4; ++r) {
            int e = wv * 12 + g * 4 + r;
            float vh = 0.f, vx = 0.f;
#pragma unroll
            for (int w = 0; w < 4; ++w) vh += P[w][e][lane];
#pragma unroll
            for (int w = 4; w < 8; ++w) vx += P[w][e][lane];
            sh[g][r] = vh; sx[g][r] = vx;
          }
        float hv[4];
#pragma unroll
        for (int r = 0; r < 4; ++r) {
          float rv = 1.f / (1.f + __expf(-(sx[0][r] + bir + sh[0][r] + bhr)));
          float zv = 1.f / (1.f + __expf(-(sx[1][r] + biz + sh[1][r] + bhz)));
          float nv = tanhf(sx[2][r] + bin_ + rv * (sh[2][r] + bhn));
          hv[r] = (1.f - zv) * nv + zv * hl[r];
          hl[r] = hv[r];
        }
        ull word = (ull)((unsigned)f2b(hv[0]) | ((unsigned)f2b(hv[1]) << 16)) |
                   ((ull)((unsigned)f2b(hv[2]) | ((unsigned)f2b(hv[3]) << 16)) << 32);
        const int toff = (c0 + fr) * 32 + wv * 16 + fq * 4;
        __hip_atomic_store((ull*)(h2t + (size_t)(i + 1) * 32768 + toff), word,
                           __ATOMIC_RELAXED, __HIP_MEMORY_SCOPE_AGENT);
        if (i == nSteps - 1) {
          *(ull*)(h2t + toff) = word;   // slot 0 for next launch
#pragma unroll
          for (int r = 0; r < 4; ++r)
            hs1[(wv * 16 + (fq << 2) + r) * HH + c] = hv[r];
        }
        asm volatile("s_waitcnt vmcnt(0)" ::: "memory");
        if (lane == 0)
          __hip_atomic_store(f1 + wv * 64 + wg, t + 1,
                             __ATOMIC_RELAXED, __HIP_MEMORY_SCOPE_AGENT);
      }
      __syncthreads();
    }
  }
}

// ---------------------------------------------------------------- final FC
__global__ __launch_bounds__(256) void fc_k(const float* __restrict__ h,
                                            const float* __restrict__ Wf,
                                            const float* __restrict__ bf,
                                            float* __restrict__ out) {
  int idx = blockIdx.x * 256 + threadIdx.x;   // grid 64 -> 16384 = 32x512
  int b = idx >> 9, o = idx & 511;
  const float4* hv = (const float4*)(h + (b << 10));
  const float4* wv = (const float4*)(Wf + (o << 10));
  float s = 0.f;
#pragma unroll 8
  for (int i = 0; i < 256; ++i) {
    float4 x = hv[i], y = wv[i];
    s += x.x * y.x + x.y * y.y + x.z * y.z + x.w * y.w;
  }
  out[idx] = s + bf[o];
}

// ---------------------------------------------------------------- launch
extern "C" void kernel_launch(void* const* d_in, const int* in_sizes, int n_in,
                              void* d_out, int out_size, void* d_ws, size_t ws_size,
                              hipStream_t stream) {
  const float* x    = (const float*)d_in[0];
  const float* Wih0 = (const float*)d_in[1];
  const float* Whh0 = (const float*)d_in[2];
  const float* bih0 = (const float*)d_in[3];
  const float* bhh0 = (const float*)d_in[4];
  const float* Wih1 = (const float*)d_in[5];
  const float* Whh1 = (const float*)d_in[6];
  const float* bih1 = (const float*)d_in[7];
  const float* bhh1 = (const float*)d_in[8];
  const float* Wfc  = (const float*)d_in[9];
  const float* bfc  = (const float*)d_in[10];
  float* out = (float*)d_out;

  // workspace layout (total ~89.5 MiB)
  char* w = (char*)d_ws;
  ushort* wi0b = (ushort*)(w);                    //  3,145,728
  ushort* wh0b = (ushort*)(w + 3145728);          //  6,291,456
  ushort* wi1b = (ushort*)(w + 9437184);          //  6,291,456
  ushort* wh1b = (ushort*)(w + 15728640);         //  6,291,456
  float*  xp   = (float*)(w + 22020096);          // 50,331,648  [128,B,3H] fp32
  ushort* h1t  = (ushort*)(w + 72351744);         //  8,454,144  129 slots h_tr[c][b]
  ushort* h2t  = (ushort*)(w + 80805888);         //  8,454,144
  float*  hs0  = (float*)(w + 89260032);          //    131,072
  float*  hs1  = (float*)(w + 89391104);          //    131,072
  int*    f0   = (int*)(w + 89522176);            //        512 (128 ints)
  int*    f1   = (int*)(w + 89522688);            //        512

  init_k<<<128, 256, 0, stream>>>((unsigned int*)h1t, (unsigned int*)h2t, f0, f1);

  cast_k<<<1536, 256, 0, stream>>>(Wih0, wi0b, (3 * HH * DIN) / 4);
  cast_k<<<3072, 256, 0, stream>>>(Whh0, wh0b, (3 * HH * HH) / 4);
  cast_k<<<3072, 256, 0, stream>>>(Wih1, wi1b, (3 * HH * HH) / 4);
  cast_k<<<3072, 256, 0, stream>>>(Whh1, wh1b, (3 * HH * HH) / 4);

  for (int ch = 0; ch < 4; ++ch) {
    const int t0 = ch * CHUNK;
    gemm_bt<<<dim3(24, 32), 256, 0, stream>>>(x, wi0b, xp, 3 * HH, DIN, t0);
    gru_fused<<<128, 512, 0, stream>>>(wh0b, wh1b, wi1b, bih0, bhh0, bih1, bhh1,
                                       xp, h1t, h2t, hs0, hs1, f0, f1, t0, CHUNK);
  }

  fc_k<<<64, 256, 0, stream>>>(hs1, Wfc, bfc, out);
}